// Round 3
// baseline (258.193 us; speedup 1.0000x reference)
//
#include <hip/hip_runtime.h>
#include <hip/hip_bf16.h>
#include <stdint.h>

// Problem constants (B=2, N=2048, C=1024, H=16, D=64)
#define SL_F 0.18033688011112043f   // SCALE * log2(e): softmax in exp2 domain

typedef unsigned short u16;
typedef unsigned int u32;
typedef __attribute__((ext_vector_type(8))) short bf16x8;   // 8 bf16 = 4 VGPRs
typedef __attribute__((ext_vector_type(4))) float f32x4;

__device__ __forceinline__ u16 f2bf(float f) {
    union { float f; u32 u; } v; v.f = f;
    return (u16)((v.u + 0x7fffu + ((v.u >> 16) & 1u)) >> 16);  // RNE
}
__device__ __forceinline__ u32 pack2bf(float a, float b) {
    union { __hip_bfloat162 h; u32 u; } p;
    p.h = __float22bfloat162_rn(make_float2(a, b));
    return p.u;
}

// async global->LDS, 16B per lane; global src may be per-lane (gather),
// LDS dest = wave-uniform base + lane*16
__device__ __forceinline__ void gl_lds16(const u16* g, u16* l) {
    __builtin_amdgcn_global_load_lds(
        (const __attribute__((address_space(1))) u32*)g,
        (__attribute__((address_space(3))) u32*)l, 16, 0, 0);
}

// ---------------- fp32 -> bf16 conversion of x, w_qkv, w_proj ----------------
__global__ __launch_bounds__(256) void convert_k(
    const float4* __restrict__ x, const float4* __restrict__ w1,
    const float4* __restrict__ w2,
    ushort4* __restrict__ xb, ushort4* __restrict__ w1b, ushort4* __restrict__ w2b)
{
    const int i = blockIdx.x * 256 + threadIdx.x;
    const int XN = 4096 * 1024 / 4, W1 = 3072 * 1024 / 4;  // W2 = 1024*1024/4
    float4 v; ushort4* dst;
    if (i < XN)            { v = x[i];            dst = &xb[i]; }
    else if (i < XN + W1)  { v = w1[i - XN];      dst = &w1b[i - XN]; }
    else                   { v = w2[i - XN - W1]; dst = &w2b[i - XN - W1]; }
    ushort4 o;
    o.x = f2bf(v.x); o.y = f2bf(v.y); o.z = f2bf(v.z); o.w = f2bf(v.w);
    *dst = o;
}

// ---------------- 256x256 QKV GEMM, 4-phase fine-interleaved pipeline --------
// Round-2 post-mortem: monolithic {vmcnt;barrier;stage;32 MFMA} per K-tile =
// the coarse phase-split m196 measured as a LOSS (no intra-wave overlap, no
// TLP at 1 block/CU -> 6000 cyc/iter). This round: the real T3/T4 mechanism.
// BK=64 K-step, 4 phases/step, 16 MFMA (one output quadrant x K=64) per phase:
//   [vmcnt(4); s_barrier]  (phases 0-2 only)
//   stage ONE half-tile of step s+1 (2 gl_lds16/wave)
//   12 ds_read_b128 (quadrant frags)          <- overlaps staging issue
//   setprio(1); 16 MFMA; setprio(0)           <- compiler emits lgkmcnt
// Halves staged in order [Ah0,Bh0,Ah1,Bh1] = quadrant consumption order
// (0,0),(1,0),(1,1),(0,1): uniform FIFO vmcnt(4) (=2 loads x 2 newest halves
// in flight) guarantees exactly the half this phase reads has landed; barrier
// makes it block-wide. Stage AFTER barrier -> WAR vs opposite dbuf is safe.
// Loads get ~3.5 phases (~700 cyc) to land. Tail: dummy re-stage of step 15
// keeps wait arithmetic uniform; vmcnt(0) once after the loop.
// LDS fragment-identity groups (16r x 32k = 1KB), 0 bank conflicts (measured).
// A "half" h: A rows {4h..4h+3, 8+4h..8+4h+3}x16 (what quadrant mq=h reads
// across both wave rows); B cols {4j+2h+t}x16. 16 groups/half = 2 loads/wave.
__global__ __launch_bounds__(512) void gemm256_qkv(
    const u16* __restrict__ A, const u16* __restrict__ Bw,
    const float* __restrict__ bias,
    u16* __restrict__ Qb, u16* __restrict__ Kb, u16* __restrict__ VTb)
{
    __shared__ __align__(16) u16 Al[2][32 * 512];   // 64 KB: 2 dbuf x 32 groups
    __shared__ __align__(16) u16 Bl[2][32 * 512];   // 64 KB
    const int tid = threadIdx.x;
    const int lane = tid & 63;
    const int w = tid >> 6;                  // 0..7
    const int la = lane & 15, qd = lane >> 4;

    // XCD-chunked swizzle (T1): 192 blocks = 8 chunks (4m x 2n) of 4x6 tiles.
    const int bid = blockIdx.x;
    const int xcd = bid & 7, ci = bid >> 3;          // ci in 0..23
    const int m0 = ((xcd >> 1) * 4 + ci / 6) * 256;  // 16 m-tiles
    const int n0 = ((xcd & 1) * 6 + ci % 6) * 256;   // 12 n-tiles

    // staging geometry: wave w owns A row-group arg[h] and B col-group bcg[h]
    // per half h (2 gl_lds16 per half: khalf 0,1)
    const int arg0 = (w & 3) + (w >> 2) * 8;         // h=0: +0, h=1: +4
    const int bcg0 = 4 * (w >> 1) + (w & 1);         // h=0: +0, h=1: +2
    const u16* As0 = A + (size_t)(m0 + arg0 * 16 + la) * 1024 + qd * 8;
    const u16* As1 = A + (size_t)(m0 + (arg0 + 4) * 16 + la) * 1024 + qd * 8;
    const u16* Bs0 = Bw + (size_t)(n0 + bcg0 * 16 + la) * 1024 + qd * 8;
    const u16* Bs1 = Bw + (size_t)(n0 + (bcg0 + 2) * 16 + la) * 1024 + qd * 8;

    auto stageA = [&](int h, int sn, int dn) {       // 2 loads (vmcnt units)
        const int rg = arg0 + h * 4;
        const u16* src = (h == 0) ? As0 : As1;
        gl_lds16(src + sn * 64,      &Al[dn][(rg * 2 + 0) * 512]);
        gl_lds16(src + sn * 64 + 32, &Al[dn][(rg * 2 + 1) * 512]);
    };
    auto stageB = [&](int h, int sn, int dn) {
        const int cg = bcg0 + h * 2;
        const u16* src = (h == 0) ? Bs0 : Bs1;
        gl_lds16(src + sn * 64,      &Bl[dn][(cg * 2 + 0) * 512]);
        gl_lds16(src + sn * 64 + 32, &Bl[dn][(cg * 2 + 1) * 512]);
    };

    f32x4 acc[8][4] = {};

    // prologue: all 4 halves of step 0 -> dbuf 0 (8 loads in flight)
    stageA(0, 0, 0); stageB(0, 0, 0); stageA(1, 0, 0); stageB(1, 0, 0);

    for (int s = 0; s < 16; ++s) {                   // K-steps of 64
        const int d = s & 1, dn = d ^ 1;
        const int sn = (s < 15) ? s + 1 : 15;        // s=15: dummy re-stage
#pragma unroll
        for (int p = 0; p < 4; ++p) {
            const int mq = (p == 1 || p == 2) ? 1 : 0;   // quadrant order
            const int nq = (p >= 2) ? 1 : 0;             // (0,0)(1,0)(1,1)(0,1)
            if (p < 3) {
                asm volatile("s_waitcnt vmcnt(4)" ::: "memory");
                __builtin_amdgcn_s_barrier();
                asm volatile("" ::: "memory");
            }
            // stage half p of step sn (order Ah0,Bh0,Ah1,Bh1)
            if (p == 0)      stageA(0, sn, dn);
            else if (p == 1) stageB(0, sn, dn);
            else if (p == 2) stageA(1, sn, dn);
            else             stageB(1, sn, dn);

            // quadrant fragments from dbuf d
            bf16x8 af[4][2], bfr[2][2];
#pragma unroll
            for (int i = 0; i < 4; i++) {
                const int rg = (w >> 2) * 8 + mq * 4 + i;
#pragma unroll
                for (int kh = 0; kh < 2; kh++)
                    af[i][kh] = *(const bf16x8*)&Al[d][(rg * 2 + kh) * 512 + lane * 8];
            }
#pragma unroll
            for (int j = 0; j < 2; j++) {
                const int cg = (w & 3) * 4 + nq * 2 + j;
#pragma unroll
                for (int kh = 0; kh < 2; kh++)
                    bfr[j][kh] = *(const bf16x8*)&Bl[d][(cg * 2 + kh) * 512 + lane * 8];
            }
            __builtin_amdgcn_s_setprio(1);
#pragma unroll
            for (int i = 0; i < 4; i++)
#pragma unroll
                for (int j = 0; j < 2; j++) {
                    f32x4 c = acc[mq * 4 + i][nq * 2 + j];
                    c = __builtin_amdgcn_mfma_f32_16x16x32_bf16(af[i][0], bfr[j][0], c, 0, 0, 0);
                    c = __builtin_amdgcn_mfma_f32_16x16x32_bf16(af[i][1], bfr[j][1], c, 0, 0, 0);
                    acc[mq * 4 + i][nq * 2 + j] = c;
                }
            __builtin_amdgcn_s_setprio(0);
        }
    }
    asm volatile("s_waitcnt vmcnt(0)" ::: "memory"); // drain dummy stages

    // Epilogue. C/D layout: col = lane&15, row = (lane>>4)*4 + reg [m89]
    // acc[a][b]: row = m0 + (w>>2)*128 + a*16 + qd*4 + r, col = n0 + (w&3)*64 + b*16 + la
#pragma unroll
    for (int jn = 0; jn < 4; jn++) {
        const int col = n0 + (w & 3) * 64 + jn * 16 + la;
        const float bv = bias[col];
        const int t = col >> 10, hd = col & 1023, h = hd >> 6, dd = hd & 63;
#pragma unroll
        for (int i = 0; i < 8; i++)
#pragma unroll
            for (int r = 0; r < 4; r++) {
                const int row = m0 + (w >> 2) * 128 + i * 16 + qd * 4 + r;
                const int bb = row >> 11, n = row & 2047;
                const int bh = bb * 16 + h;
                const u16 val = f2bf(acc[i][jn][r] + bv);
                if (t == 0)      Qb[((size_t)bh * 2048 + n) * 64 + dd] = val;
                else if (t == 1) Kb[((size_t)bh * 2048 + n) * 64 + dd] = val;
                else             VTb[((size_t)bh * 64 + dd) * 2048 + n] = val;
            }
    }
}

// ---------------- NT bf16 GEMM (proj): out[m,n] = sum_k A[m,k]*W[n,k] + bias -
// Tile 128 x NT, BK=32, 256 thr (4 waves, 2x2; wave-tile 64 x NT/2).
// LDS staged via global_load_lds (fragment-ordered), DOUBLE-BUFFERED.
// EPI 1: proj epilogue (fp32 out + bias). (EPI 0 path retained but unused.)
template<int NT, int EPI>
__global__ __launch_bounds__(256) void gemm_nt(
    const u16* __restrict__ A, const u16* __restrict__ Bw,
    const float* __restrict__ bias,
    u16* __restrict__ Qb, u16* __restrict__ Kb, u16* __restrict__ VTb,
    float* __restrict__ Out)
{
    constexpr int NBF = NT / 32;        // B-frags per wave (4 or 2)
    constexpr int BGRP = NT / 16;       // 16-row groups in B tile (8 or 4)
    __shared__ __align__(16) u16 Al[2][8 * 512];
    __shared__ __align__(16) u16 Bl[2][BGRP * 512];
    const int tid = threadIdx.x;
    const int lane = tid & 63;
    const int w = tid >> 6;
    const int la = lane & 15, qd = lane >> 4;
    const int K = 1024;
    const int m0 = blockIdx.y * 128;
    const int n0 = blockIdx.x * NT;
    const int wm = (w >> 1) * 64, wn = (w & 1) * (NT / 2);

    const u16* Ag0 = A + (size_t)(m0 + (2 * w) * 16 + la) * K + qd * 8;
    const u16* Ag1 = A + (size_t)(m0 + (2 * w + 1) * 16 + la) * K + qd * 8;
    const int bg0 = (BGRP == 8) ? 2 * w : w;
    const u16* Bg0 = Bw + (size_t)(n0 + bg0 * 16 + la) * K + qd * 8;
    const u16* Bg1 = Bw + (size_t)(n0 + (2 * w + 1) * 16 + la) * K + qd * 8;

    auto stage = [&](int k0, int b) {
        gl_lds16(Ag0 + k0, &Al[b][(2 * w) * 512]);
        gl_lds16(Ag1 + k0, &Al[b][(2 * w + 1) * 512]);
        gl_lds16(Bg0 + k0, &Bl[b][bg0 * 512]);
        if (BGRP == 8)
            gl_lds16(Bg1 + k0, &Bl[b][(2 * w + 1) * 512]);
    };

    f32x4 acc[4][NBF] = {};
    int buf = 0;
    stage(0, 0);

    for (int k0 = 0; k0 < K; k0 += 32) {
        __syncthreads();                       // drains prev prefetch (vmcnt 0)
        if (k0 + 32 < K) stage(k0 + 32, buf ^ 1);

        bf16x8 af[4], bfr[NBF];
#pragma unroll
        for (int i = 0; i < 4; i++)
            af[i] = *(const bf16x8*)&Al[buf][(((unsigned)wm >> 4) + i) * 512 + lane * 8];
#pragma unroll
        for (int j = 0; j < NBF; j++)
            bfr[j] = *(const bf16x8*)&Bl[buf][(((unsigned)wn >> 4) + j) * 512 + lane * 8];
#pragma unroll
        for (int i = 0; i < 4; i++)
#pragma unroll
            for (int j = 0; j < NBF; j++)
                acc[i][j] = __builtin_amdgcn_mfma_f32_16x16x32_bf16(
                    af[i], bfr[j], acc[i][j], 0, 0, 0);
        buf ^= 1;
    }

    // Epilogue. C/D layout: col = lane&15, row = (lane>>4)*4 + reg  [m89-verified]
#pragma unroll
    for (int j = 0; j < NBF; j++) {
        const int col = n0 + wn + j * 16 + la;
        const float bv = bias[col];
        if (EPI == 0) {
            const int t = col >> 10, hd = col & 1023, h = hd >> 6, d = hd & 63;
#pragma unroll
            for (int i = 0; i < 4; i++)
#pragma unroll
                for (int r = 0; r < 4; r++) {
                    const int row = m0 + wm + i * 16 + qd * 4 + r;
                    const int b = row >> 11, n = row & 2047;
                    const int bh = b * 16 + h;
                    const u16 val = f2bf(acc[i][j][r] + bv);
                    if (t == 0)      Qb[((size_t)bh * 2048 + n) * 64 + d] = val;
                    else if (t == 1) Kb[((size_t)bh * 2048 + n) * 64 + d] = val;
                    else             VTb[((size_t)bh * 64 + d) * 2048 + n] = val;
                }
        } else {
#pragma unroll
            for (int i = 0; i < 4; i++)
#pragma unroll
                for (int r = 0; r < 4; r++) {
                    const int row = m0 + wm + i * 16 + qd * 4 + r;
                    Out[(size_t)row * 1024 + col] = acc[i][j][r] + bv;
                }
        }
    }
}

// ---------------- causal flash attention, LDS-staged, j-step 128 -------------
// 1-D grid of 512: bh = id&31 (XCD affinity -> K/V L2-resident, FETCH 12 MB),
// pair = id>>5 does Q-tiles {pair, 31-pair}. j-tiles of 128 (TWO 64-subtiles
// per barrier): floor(t/2)+1 iters per tile = 17 iters/block for every pair —
// halves the per-iter fixed costs (barrier + vmcnt(0) drain) vs j-step 64.
// K/V double-buffered LDS staged by gl_lds16 (each byte loaded once per BLOCK,
// 4x less L1 traffic than per-wave register loads). Softmax: fixed m=0
// (|S*SL| << 127; identical softmax), S computed transposed (A=K, B=Q -> lane
// owns one q-row, no cross-lane reductions per iter); P round-trips per-wave
// LDS buffer reused for both j-halves (same-wave DS is in-order).
__global__ __launch_bounds__(256) void attn_k(
    const u16* __restrict__ Qb, const u16* __restrict__ Kb,
    const u16* __restrict__ VTb, u16* __restrict__ Ob)
{
    __shared__ __align__(16) u16 Kl[2][16 * 512];   // 32 KB: chunk ck=c*2+h
    __shared__ __align__(16) u16 Vl[2][16 * 512];   // 32 KB: chunk cv=c2*4+kc
    __shared__ __align__(16) u16 Pl[4][16 * 72];    // per-wave P, stride 72
    const int bh = blockIdx.x & 31;
    const int pair = blockIdx.x >> 5;               // 0..15
    const int tid = threadIdx.x;
    const int lane = tid & 63;
    const int w = tid >> 6;
    const int la = lane & 15, qd = lane >> 4;

    const u16* Kbase = Kb + (size_t)bh * 2048 * 64;
    const u16* Vbase = VTb + (size_t)bh * 64 * 2048;
    u16* Pw = &Pl[w][0];

    // staging: wave w stages K chunks 4w..4w+3 and V chunks 4w..4w+3
    u32 ksrc[4], vsrc[4];
#pragma unroll
    for (int t = 0; t < 4; t++) {
        const int ck = 4 * w + t;
        ksrc[t] = (u32)((ck >> 1) * 16 + la) * 64 + (ck & 1) * 32 + qd * 8;
        vsrc[t] = (u32)((ck >> 2) * 16 + la) * 2048 + (ck & 3) * 32 + qd * 8;
    }
    auto stage = [&](int j0, int b) {
#pragma unroll
        for (int t = 0; t < 4; t++) {
            gl_lds16(Kbase + (u32)j0 * 64 + ksrc[t], &Kl[b][(4 * w + t) * 512]);
            gl_lds16(Vbase + (u32)j0 + vsrc[t], &Vl[b][(4 * w + t) * 512]);
        }
    };

    int buf = 0;
    stage(0, 0);                                    // prologue for first tile

    for (int half = 0; half < 2; half++) {
        const int tile = (half == 0) ? pair : 31 - pair;
        const int q0 = tile * 64 + w * 16;
        const int jmax = (tile >> 1) * 128;         // last j128-tile start
        const int qrow = q0 + la;                   // this lane's q-row

        const u16* Qp = Qb + ((size_t)bh * 2048 + q0 + la) * 64 + qd * 8;
        const bf16x8 qf0 = *(const bf16x8*)Qp;
        const bf16x8 qf1 = *(const bf16x8*)(Qp + 32);

        f32x4 o[4] = {};
        float lsum = 0.f;

        for (int j0 = 0; j0 <= jmax; j0 += 128) {
            __syncthreads();   // drains prev prefetch (vmcnt 0, all waves)

            const int nj = (j0 + 128 <= jmax) ? (j0 + 128) : ((half == 0) ? 0 : -1);
            if (nj >= 0) stage(nj, buf ^ 1);

            // S^T = K Q^T : 8 j-subtiles; D[row=j (qd*4+r), col=q (la)]
            f32x4 s[8];
#pragma unroll
            for (int c = 0; c < 8; c++) {
                f32x4 z = {};
                const bf16x8 kf0 = *(const bf16x8*)&Kl[buf][(c * 2 + 0) * 512 + lane * 8];
                const bf16x8 kf1 = *(const bf16x8*)&Kl[buf][(c * 2 + 1) * 512 + lane * 8];
                z = __builtin_amdgcn_mfma_f32_16x16x32_bf16(kf0, qf0, z, 0, 0, 0);
                z = __builtin_amdgcn_mfma_f32_16x16x32_bf16(kf1, qf1, z, 0, 0, 0);
                s[c] = z;
            }

            // p = exp2(s * SL); causal mask only on the diagonal-containing tile
            if (j0 == jmax) {
#pragma unroll
                for (int c = 0; c < 8; c++)
#pragma unroll
                    for (int r = 0; r < 4; r++) {
                        const int j = j0 + c * 16 + qd * 4 + r;
                        float v = s[c][r] * SL_F;
                        v = (j > qrow) ? -1e30f : v;
                        s[c][r] = __builtin_amdgcn_exp2f(v);
                    }
            } else {
#pragma unroll
                for (int c = 0; c < 8; c++)
#pragma unroll
                    for (int r = 0; r < 4; r++)
                        s[c][r] = __builtin_amdgcn_exp2f(s[c][r] * SL_F);
            }
#pragma unroll
            for (int c = 0; c < 8; c++)
#pragma unroll
                for (int r = 0; r < 4; r++)
                    lsum += s[c][r];

            // PV in two j-64 halves, reusing the per-wave P buffer (same-wave
            // DS ops are in-order: the hh=1 writes cannot pass hh=0 reads)
#pragma unroll
            for (int hh = 0; hh < 2; hh++) {
#pragma unroll
                for (int c = 0; c < 4; c++) {
                    uint2 pw;
                    pw.x = pack2bf(s[hh * 4 + c][0], s[hh * 4 + c][1]);
                    pw.y = pack2bf(s[hh * 4 + c][2], s[hh * 4 + c][3]);
                    *(uint2*)&Pw[la * 72 + c * 16 + qd * 4] = pw;
                }
                const bf16x8 pf0 = *(const bf16x8*)&Pw[la * 72 + qd * 8];
                const bf16x8 pf1 = *(const bf16x8*)&Pw[la * 72 + 32 + qd * 8];
#pragma unroll
                for (int c2 = 0; c2 < 4; c2++) {
                    const bf16x8 vf0 = *(const bf16x8*)&Vl[buf][(c2 * 4 + hh * 2 + 0) * 512 + lane * 8];
                    const bf16x8 vf1 = *(const bf16x8*)&Vl[buf][(c2 * 4 + hh * 2 + 1) * 512 + lane * 8];
                    o[c2] = __builtin_amdgcn_mfma_f32_16x16x32_bf16(pf0, vf0, o[c2], 0, 0, 0);
                    o[c2] = __builtin_amdgcn_mfma_f32_16x16x32_bf16(pf1, vf1, o[c2], 0, 0, 0);
                }
            }
            buf ^= 1;
        }

        // reduce l across the 4 quads (lane la holds row la's partials)
        lsum += __shfl_xor(lsum, 16, 64);
        lsum += __shfl_xor(lsum, 32, 64);
        float rinv[4];
#pragma unroll
        for (int r = 0; r < 4; r++)
            rinv[r] = 1.0f / __shfl(lsum, qd * 4 + r, 64);

        // write flat [B,H,N,D] bf16 (== reference's faithful scrambled reshape)
        u16* Op = Ob + (size_t)bh * 2048 * 64;
#pragma unroll
        for (int c2 = 0; c2 < 4; c2++)
#pragma unroll
            for (int r = 0; r < 4; r++) {
                const int row = q0 + qd * 4 + r;
                Op[(size_t)row * 64 + c2 * 16 + la] = f2bf(o[c2][r] * rinv[r]);
            }
    }
}

// ---------------- launch -----------------------------------------------------
extern "C" void kernel_launch(void* const* d_in, const int* in_sizes, int n_in,
                              void* d_out, int out_size, void* d_ws, size_t ws_size,
                              hipStream_t stream)
{
    const float* x     = (const float*)d_in[0];
    // d_in[1] = attention_mask: structurally causal tril; enforced analytically.
    const float* wqkv  = (const float*)d_in[2];
    const float* bqkv  = (const float*)d_in[3];
    const float* wproj = (const float*)d_in[4];
    const float* bproj = (const float*)d_in[5];
    float* out = (float*)d_out;

    // workspace layout (u16 units), ~50 MB total
    u16* ws     = (u16*)d_ws;
    u16* xb     = ws;                       // 4096*1024
    u16* wqkvb  = xb + 4096 * 1024;         // 3072*1024
    u16* wprojb = wqkvb + 3072 * 1024;      // 1024*1024
    u16* Qb     = wprojb + 1024 * 1024;     // 32*2048*64  [B,H,N,D]
    u16* Kb     = Qb + 32 * 2048 * 64;      // 32*2048*64  [B,H,N,D]
    u16* VTb    = Kb + 32 * 2048 * 64;      // 32*64*2048  [B,H,D,N]
    u16* Ob     = VTb + 32 * 2048 * 64;     // 32*2048*64  [B,H,N,D] == scrambled [B*N, C]

    convert_k<<<dim3(8192), dim3(256), 0, stream>>>(
        (const float4*)x, (const float4*)wqkv, (const float4*)wproj,
        (ushort4*)xb, (ushort4*)wqkvb, (ushort4*)wprojb);

    gemm256_qkv<<<dim3(192), dim3(512), 0, stream>>>(
        xb, wqkvb, bqkv, Qb, Kb, VTb);

    attn_k<<<dim3(512), dim3(256), 0, stream>>>(Qb, Kb, VTb, Ob);

    // proj: 128x64 tile -> 512 blocks = 2/CU
    gemm_nt<64, 1><<<dim3(16, 32), dim3(256), 0, stream>>>(
        Ob, wprojb, bproj, (u16*)nullptr, (u16*)nullptr, (u16*)nullptr, out);
}

// Round 5
// 234.216 us; speedup vs baseline: 1.1024x; 1.1024x over previous
//
#include <hip/hip_runtime.h>
#include <hip/hip_bf16.h>
#include <stdint.h>

// Problem constants (B=2, N=2048, C=1024, H=16, D=64)
#define SL_F 0.18033688011112043f   // SCALE * log2(e): softmax in exp2 domain

typedef unsigned short u16;
typedef unsigned int u32;
typedef __attribute__((ext_vector_type(8))) short bf16x8;   // 8 bf16 = 4 VGPRs
typedef __attribute__((ext_vector_type(4))) float f32x4;

__device__ __forceinline__ u16 f2bf(float f) {
    union { float f; u32 u; } v; v.f = f;
    return (u16)((v.u + 0x7fffu + ((v.u >> 16) & 1u)) >> 16);  // RNE
}
__device__ __forceinline__ u32 pack2bf(float a, float b) {
    union { __hip_bfloat162 h; u32 u; } p;
    p.h = __float22bfloat162_rn(make_float2(a, b));
    return p.u;
}

// async global->LDS, 16B per lane; global src may be per-lane (gather),
// LDS dest = wave-uniform base + lane*16
__device__ __forceinline__ void gl_lds16(const u16* g, u16* l) {
    __builtin_amdgcn_global_load_lds(
        (const __attribute__((address_space(1))) u32*)g,
        (__attribute__((address_space(3))) u32*)l, 16, 0, 0);
}

// ---------------- fp32 -> bf16 conversion of x, w_qkv, w_proj ----------------
__global__ __launch_bounds__(256) void convert_k(
    const float4* __restrict__ x, const float4* __restrict__ w1,
    const float4* __restrict__ w2,
    ushort4* __restrict__ xb, ushort4* __restrict__ w1b, ushort4* __restrict__ w2b)
{
    const int i = blockIdx.x * 256 + threadIdx.x;
    const int XN = 4096 * 1024 / 4, W1 = 3072 * 1024 / 4;  // W2 = 1024*1024/4
    float4 v; ushort4* dst;
    if (i < XN)            { v = x[i];            dst = &xb[i]; }
    else if (i < XN + W1)  { v = w1[i - XN];      dst = &w1b[i - XN]; }
    else                   { v = w2[i - XN - W1]; dst = &w2b[i - XN - W1]; }
    ushort4 o;
    o.x = f2bf(v.x); o.y = f2bf(v.y); o.z = f2bf(v.z); o.w = f2bf(v.w);
    *dst = o;
}

// ---------------- NT bf16 GEMM body: out[m,n] = sum_k A[m,k]*W[n,k] (+bias) --
// ROUND-0 PROVEN STRUCTURE (restored after two failed counted-vmcnt rewrites:
// r2 coarse 80us, r3 fine 4-phase 88us vs this at 63us — both pipelined ports
// lost to the plain 2-barrier dbuf loop; see m196 coarse-split lesson).
// Tile 128 x NT, BK=32, 256 thr (4 waves, 2x2; wave-tile 64 x NT/2).
// LDS staged via global_load_lds (fragment-ordered), DOUBLE-BUFFERED: one
// barrier per k-iter. NOTE: per-CU LDS traffic ~75-90 B/cyc of the ~85-112
// ceiling -> LDS-port co-limited; do not expect TLP/pipeline tweaks to help.
// EPI 0: qkv scatter. Q,K: [B,H,N,D] bf16 direct (32B-run stores).
//        V (t==2 blocks, block-uniform): per-wave LDS transpose -> coalesced
//        16B/lane stores to VT [B,H,D,N]. (r4 fix: store vector is bf16x8 =
//        16B; the r3 ushort4=8B version covered only HALF the elements.)
// EPI 1: proj epilogue (fp32 out + bias).
template<int NT, int EPI>
__device__ __forceinline__ void gemm_body(
    u16* SMEM,
    const u16* __restrict__ A, const u16* __restrict__ Bw,
    const float* __restrict__ bias,
    u16* __restrict__ Qb, u16* __restrict__ Kb, u16* __restrict__ VTb,
    float* __restrict__ Out)
{
    constexpr int NBF = NT / 32;        // B-frags per wave (4 or 2)
    constexpr int BGRP = NT / 16;       // 16-row groups in B tile (8 or 4)
    u16 (*Al)[8 * 512] = (u16 (*)[8 * 512])SMEM;              // 2 x 8 groups
    u16 (*Bl)[BGRP * 512] = (u16 (*)[BGRP * 512])(SMEM + 2 * 8 * 512);
    const int tid = threadIdx.x;
    const int lane = tid & 63;
    const int w = tid >> 6;
    const int la = lane & 15, qd = lane >> 4;
    const int K = 1024;
    const int m0 = blockIdx.y * 128;
    const int n0 = blockIdx.x * NT;
    const int wm = (w >> 1) * 64, wn = (w & 1) * (NT / 2);

    const u16* Ag0 = A + (size_t)(m0 + (2 * w) * 16 + la) * K + qd * 8;
    const u16* Ag1 = A + (size_t)(m0 + (2 * w + 1) * 16 + la) * K + qd * 8;
    const int bg0 = (BGRP == 8) ? 2 * w : w;
    const u16* Bg0 = Bw + (size_t)(n0 + bg0 * 16 + la) * K + qd * 8;
    const u16* Bg1 = Bw + (size_t)(n0 + (2 * w + 1) * 16 + la) * K + qd * 8;

    auto stage = [&](int k0, int b) {
        gl_lds16(Ag0 + k0, &Al[b][(2 * w) * 512]);
        gl_lds16(Ag1 + k0, &Al[b][(2 * w + 1) * 512]);
        gl_lds16(Bg0 + k0, &Bl[b][bg0 * 512]);
        if (BGRP == 8)
            gl_lds16(Bg1 + k0, &Bl[b][(2 * w + 1) * 512]);
    };

    f32x4 acc[4][NBF] = {};
    int buf = 0;
    stage(0, 0);

    for (int k0 = 0; k0 < K; k0 += 32) {
        __syncthreads();                       // drains prev prefetch (vmcnt 0)
        if (k0 + 32 < K) stage(k0 + 32, buf ^ 1);

        bf16x8 af[4], bfr[NBF];
#pragma unroll
        for (int i = 0; i < 4; i++)
            af[i] = *(const bf16x8*)&Al[buf][(((unsigned)wm >> 4) + i) * 512 + lane * 8];
#pragma unroll
        for (int j = 0; j < NBF; j++)
            bfr[j] = *(const bf16x8*)&Bl[buf][(((unsigned)wn >> 4) + j) * 512 + lane * 8];
#pragma unroll
        for (int i = 0; i < 4; i++)
#pragma unroll
            for (int j = 0; j < NBF; j++)
                acc[i][j] = __builtin_amdgcn_mfma_f32_16x16x32_bf16(
                    af[i], bfr[j], acc[i][j], 0, 0, 0);
        buf ^= 1;
    }

    // Epilogue. C/D layout: col = lane&15, row = (lane>>4)*4 + reg  [m89-verified]
    if (EPI == 0 && (n0 >> 10) == 2) {
        // ---- V-transpose path (whole block is V: n0 in [2048,3072)) ----
        // Per-wave LDS transpose, stride 72 u16 (144 B = 9x16, rows 16B-aligned).
        // Wave region: 32 x 72 u16 = 4.6 KB; 4 waves = 18.4 KB of the 32 KB
        // GEMM buffers (free after the sync). Same-wave DS ops are in-order.
        __syncthreads();                       // all waves done reading Al/Bl
        u16* Wl = SMEM + w * 2304;
        const int h2 = ((n0 & 1023) + wn) >> 6;      // head, block+wave uniform
        const int bh = (m0 >> 11) * 16 + h2;
        const int nb = (m0 + wm) & 2047;             // n base of this wave
#pragma unroll
        for (int P = 0; P < 2; P++) {                // d-halves 0..31, 32..63
#pragma unroll
            for (int jj = 0; jj < 2; jj++) {
                const int j = 2 * P + jj;
                const float bv = bias[n0 + wn + j * 16 + la];
#pragma unroll
                for (int i = 0; i < 4; i++) {
                    uint2 pw;
                    pw.x = pack2bf(acc[i][j][0] + bv, acc[i][j][1] + bv);
                    pw.y = pack2bf(acc[i][j][2] + bv, acc[i][j][3] + bv);
                    // row = d_local (jj*16+la), col = n_local (i*16+qd*4)
                    *(uint2*)&Wl[(jj * 16 + la) * 72 + i * 16 + qd * 4] = pw;
                }
            }
            // read back 16B/lane: 8 lanes x 8 u16 = full 64-col row coverage
#pragma unroll
            for (int it = 0; it < 4; it++) {
                const int dl = it * 8 + (lane >> 3);         // 0..31
                const int nc = (lane & 7) * 8;               // n chunk (8 u16)
                const bf16x8 v8 = *(const bf16x8*)&Wl[dl * 72 + nc];
                *(bf16x8*)&VTb[((size_t)bh * 64 + P * 32 + dl) * 2048 + nb + nc] = v8;
            }
        }
    } else {
#pragma unroll
        for (int j = 0; j < NBF; j++) {
            const int col = n0 + wn + j * 16 + la;
            const float bv = bias[col];
            if (EPI == 0) {
                const int t = col >> 10, hd = col & 1023, h = hd >> 6, d = hd & 63;
#pragma unroll
                for (int i = 0; i < 4; i++)
#pragma unroll
                    for (int r = 0; r < 4; r++) {
                        const int row = m0 + wm + i * 16 + qd * 4 + r;
                        const int b = row >> 11, n = row & 2047;
                        const int bh = b * 16 + h;
                        const u16 val = f2bf(acc[i][j][r] + bv);
                        if (t == 0)      Qb[((size_t)bh * 2048 + n) * 64 + d] = val;
                        else             Kb[((size_t)bh * 2048 + n) * 64 + d] = val;
                    }
            } else {
#pragma unroll
                for (int i = 0; i < 4; i++)
#pragma unroll
                    for (int r = 0; r < 4; r++) {
                        const int row = m0 + wm + i * 16 + qd * 4 + r;
                        Out[(size_t)row * 1024 + col] = acc[i][j][r] + bv;
                    }
            }
        }
    }
}

// Distinct kernel names so rocprof attributes QKV vs proj separately.
__global__ __launch_bounds__(256) void qkv_gemm(
    const u16* __restrict__ A, const u16* __restrict__ Bw,
    const float* __restrict__ bias,
    u16* __restrict__ Qb, u16* __restrict__ Kb, u16* __restrict__ VTb)
{
    __shared__ __align__(16) u16 SMEM[2 * 8 * 512 + 2 * 8 * 512];   // 32 KB
    gemm_body<128, 0>(SMEM, A, Bw, bias, Qb, Kb, VTb, nullptr);
}

__global__ __launch_bounds__(256) void proj_gemm(
    const u16* __restrict__ A, const u16* __restrict__ Bw,
    const float* __restrict__ bias, float* __restrict__ Out)
{
    __shared__ __align__(16) u16 SMEM[2 * 8 * 512 + 2 * 4 * 512];   // 24 KB
    gemm_body<64, 1>(SMEM, A, Bw, bias, nullptr, nullptr, nullptr, Out);
}

// ---------------- causal flash attention, LDS-staged, j-step 128 -------------
// 1-D grid of 512: bh = id&31 (XCD affinity -> K/V L2-resident, FETCH 12 MB),
// pair = id>>5 does Q-tiles {pair, 31-pair}. j-tiles of 128 (TWO 64-subtiles
// per barrier): floor(t/2)+1 iters per tile = 17 iters/block for every pair —
// halves the per-iter fixed costs (barrier + vmcnt(0) drain) vs j-step 64.
// K/V double-buffered LDS staged by gl_lds16 (each byte loaded once per BLOCK,
// 4x less L1 traffic than per-wave register loads). Softmax: fixed m=0
// (|S*SL| << 127; identical softmax), S computed transposed (A=K, B=Q -> lane
// owns one q-row, no cross-lane reductions per iter); P round-trips per-wave
// LDS buffer reused for both j-halves (same-wave DS is in-order).
__global__ __launch_bounds__(256) void attn_k(
    const u16* __restrict__ Qb, const u16* __restrict__ Kb,
    const u16* __restrict__ VTb, u16* __restrict__ Ob)
{
    __shared__ __align__(16) u16 Kl[2][16 * 512];   // 32 KB: chunk ck=c*2+h
    __shared__ __align__(16) u16 Vl[2][16 * 512];   // 32 KB: chunk cv=c2*4+kc
    __shared__ __align__(16) u16 Pl[4][16 * 72];    // per-wave P, stride 72
    const int bh = blockIdx.x & 31;
    const int pair = blockIdx.x >> 5;               // 0..15
    const int tid = threadIdx.x;
    const int lane = tid & 63;
    const int w = tid >> 6;
    const int la = lane & 15, qd = lane >> 4;

    const u16* Kbase = Kb + (size_t)bh * 2048 * 64;
    const u16* Vbase = VTb + (size_t)bh * 64 * 2048;
    u16* Pw = &Pl[w][0];

    // staging: wave w stages K chunks 4w..4w+3 and V chunks 4w..4w+3
    u32 ksrc[4], vsrc[4];
#pragma unroll
    for (int t = 0; t < 4; t++) {
        const int ck = 4 * w + t;
        ksrc[t] = (u32)((ck >> 1) * 16 + la) * 64 + (ck & 1) * 32 + qd * 8;
        vsrc[t] = (u32)((ck >> 2) * 16 + la) * 2048 + (ck & 3) * 32 + qd * 8;
    }
    auto stage = [&](int j0, int b) {
#pragma unroll
        for (int t = 0; t < 4; t++) {
            gl_lds16(Kbase + (u32)j0 * 64 + ksrc[t], &Kl[b][(4 * w + t) * 512]);
            gl_lds16(Vbase + (u32)j0 + vsrc[t], &Vl[b][(4 * w + t) * 512]);
        }
    };

    int buf = 0;
    stage(0, 0);                                    // prologue for first tile

    for (int half = 0; half < 2; half++) {
        const int tile = (half == 0) ? pair : 31 - pair;
        const int q0 = tile * 64 + w * 16;
        const int jmax = (tile >> 1) * 128;         // last j128-tile start
        const int qrow = q0 + la;                   // this lane's q-row

        const u16* Qp = Qb + ((size_t)bh * 2048 + q0 + la) * 64 + qd * 8;
        const bf16x8 qf0 = *(const bf16x8*)Qp;
        const bf16x8 qf1 = *(const bf16x8*)(Qp + 32);

        f32x4 o[4] = {};
        float lsum = 0.f;

        for (int j0 = 0; j0 <= jmax; j0 += 128) {
            __syncthreads();   // drains prev prefetch (vmcnt 0, all waves)

            const int nj = (j0 + 128 <= jmax) ? (j0 + 128) : ((half == 0) ? 0 : -1);
            if (nj >= 0) stage(nj, buf ^ 1);

            // S^T = K Q^T : 8 j-subtiles; D[row=j (qd*4+r), col=q (la)]
            f32x4 s[8];
#pragma unroll
            for (int c = 0; c < 8; c++) {
                f32x4 z = {};
                const bf16x8 kf0 = *(const bf16x8*)&Kl[buf][(c * 2 + 0) * 512 + lane * 8];
                const bf16x8 kf1 = *(const bf16x8*)&Kl[buf][(c * 2 + 1) * 512 + lane * 8];
                z = __builtin_amdgcn_mfma_f32_16x16x32_bf16(kf0, qf0, z, 0, 0, 0);
                z = __builtin_amdgcn_mfma_f32_16x16x32_bf16(kf1, qf1, z, 0, 0, 0);
                s[c] = z;
            }

            // p = exp2(s * SL); causal mask only on the diagonal-containing tile
            if (j0 == jmax) {
#pragma unroll
                for (int c = 0; c < 8; c++)
#pragma unroll
                    for (int r = 0; r < 4; r++) {
                        const int j = j0 + c * 16 + qd * 4 + r;
                        float v = s[c][r] * SL_F;
                        v = (j > qrow) ? -1e30f : v;
                        s[c][r] = __builtin_amdgcn_exp2f(v);
                    }
            } else {
#pragma unroll
                for (int c = 0; c < 8; c++)
#pragma unroll
                    for (int r = 0; r < 4; r++)
                        s[c][r] = __builtin_amdgcn_exp2f(s[c][r] * SL_F);
            }
#pragma unroll
            for (int c = 0; c < 8; c++)
#pragma unroll
                for (int r = 0; r < 4; r++)
                    lsum += s[c][r];

            // PV in two j-64 halves, reusing the per-wave P buffer (same-wave
            // DS ops are in-order: the hh=1 writes cannot pass hh=0 reads)
#pragma unroll
            for (int hh = 0; hh < 2; hh++) {
#pragma unroll
                for (int c = 0; c < 4; c++) {
                    uint2 pw;
                    pw.x = pack2bf(s[hh * 4 + c][0], s[hh * 4 + c][1]);
                    pw.y = pack2bf(s[hh * 4 + c][2], s[hh * 4 + c][3]);
                    *(uint2*)&Pw[la * 72 + c * 16 + qd * 4] = pw;
                }
                const bf16x8 pf0 = *(const bf16x8*)&Pw[la * 72 + qd * 8];
                const bf16x8 pf1 = *(const bf16x8*)&Pw[la * 72 + 32 + qd * 8];
#pragma unroll
                for (int c2 = 0; c2 < 4; c2++) {
                    const bf16x8 vf0 = *(const bf16x8*)&Vl[buf][(c2 * 4 + hh * 2 + 0) * 512 + lane * 8];
                    const bf16x8 vf1 = *(const bf16x8*)&Vl[buf][(c2 * 4 + hh * 2 + 1) * 512 + lane * 8];
                    o[c2] = __builtin_amdgcn_mfma_f32_16x16x32_bf16(pf0, vf0, o[c2], 0, 0, 0);
                    o[c2] = __builtin_amdgcn_mfma_f32_16x16x32_bf16(pf1, vf1, o[c2], 0, 0, 0);
                }
            }
            buf ^= 1;
        }

        // reduce l across the 4 quads (lane la holds row la's partials)
        lsum += __shfl_xor(lsum, 16, 64);
        lsum += __shfl_xor(lsum, 32, 64);
        float rinv[4];
#pragma unroll
        for (int r = 0; r < 4; r++)
            rinv[r] = 1.0f / __shfl(lsum, qd * 4 + r, 64);

        // write flat [B,H,N,D] bf16 (== reference's faithful scrambled reshape)
        u16* Op = Ob + (size_t)bh * 2048 * 64;
#pragma unroll
        for (int c2 = 0; c2 < 4; c2++)
#pragma unroll
            for (int r = 0; r < 4; r++) {
                const int row = q0 + qd * 4 + r;
                Op[(size_t)row * 64 + c2 * 16 + la] = f2bf(o[c2][r] * rinv[r]);
            }
    }
}

// ---------------- launch -----------------------------------------------------
extern "C" void kernel_launch(void* const* d_in, const int* in_sizes, int n_in,
                              void* d_out, int out_size, void* d_ws, size_t ws_size,
                              hipStream_t stream)
{
    const float* x     = (const float*)d_in[0];
    // d_in[1] = attention_mask: structurally causal tril; enforced analytically.
    const float* wqkv  = (const float*)d_in[2];
    const float* bqkv  = (const float*)d_in[3];
    const float* wproj = (const float*)d_in[4];
    const float* bproj = (const float*)d_in[5];
    float* out = (float*)d_out;

    // workspace layout (u16 units), ~50 MB total
    u16* ws     = (u16*)d_ws;
    u16* xb     = ws;                       // 4096*1024
    u16* wqkvb  = xb + 4096 * 1024;         // 3072*1024
    u16* wprojb = wqkvb + 3072 * 1024;      // 1024*1024
    u16* Qb     = wprojb + 1024 * 1024;     // 32*2048*64  [B,H,N,D]
    u16* Kb     = Qb + 32 * 2048 * 64;      // 32*2048*64  [B,H,N,D]
    u16* VTb    = Kb + 32 * 2048 * 64;      // 32*64*2048  [B,H,D,N]
    u16* Ob     = VTb + 32 * 2048 * 64;     // 32*2048*64  [B,H,N,D] == scrambled [B*N, C]

    convert_k<<<dim3(8192), dim3(256), 0, stream>>>(
        (const float4*)x, (const float4*)wqkv, (const float4*)wproj,
        (ushort4*)xb, (ushort4*)wqkvb, (ushort4*)wprojb);

    qkv_gemm<<<dim3(24, 32), dim3(256), 0, stream>>>(
        xb, wqkvb, bqkv, Qb, Kb, VTb);

    attn_k<<<dim3(512), dim3(256), 0, stream>>>(Qb, Kb, VTb, Ob);

    // proj: 128x64 tile -> 512 blocks = 2/CU
    proj_gemm<<<dim3(16, 32), dim3(256), 0, stream>>>(
        Ob, wprojb, bproj, out);
}

// Round 6
// 228.677 us; speedup vs baseline: 1.1291x; 1.0242x over previous
//
#include <hip/hip_runtime.h>
#include <hip/hip_bf16.h>
#include <stdint.h>

// Problem constants (B=2, N=2048, C=1024, H=16, D=64)
#define SL_F 0.18033688011112043f   // SCALE * log2(e): softmax in exp2 domain

typedef unsigned short u16;
typedef unsigned int u32;
typedef __attribute__((ext_vector_type(8))) short bf16x8;   // 8 bf16 = 4 VGPRs
typedef __attribute__((ext_vector_type(4))) float f32x4;

__device__ __forceinline__ u16 f2bf(float f) {
    union { float f; u32 u; } v; v.f = f;
    return (u16)((v.u + 0x7fffu + ((v.u >> 16) & 1u)) >> 16);  // RNE
}
__device__ __forceinline__ u32 pack2bf(float a, float b) {
    union { __hip_bfloat162 h; u32 u; } p;
    p.h = __float22bfloat162_rn(make_float2(a, b));
    return p.u;
}

// async global->LDS, 16B per lane; global src may be per-lane (gather),
// LDS dest = wave-uniform base + lane*16
__device__ __forceinline__ void gl_lds16(const u16* g, u16* l) {
    __builtin_amdgcn_global_load_lds(
        (const __attribute__((address_space(1))) u32*)g,
        (__attribute__((address_space(3))) u32*)l, 16, 0, 0);
}

// ---------------- fp32 -> bf16 conversion of x, w_qkv, w_proj ----------------
__global__ __launch_bounds__(256) void convert_k(
    const float4* __restrict__ x, const float4* __restrict__ w1,
    const float4* __restrict__ w2,
    ushort4* __restrict__ xb, ushort4* __restrict__ w1b, ushort4* __restrict__ w2b)
{
    const int i = blockIdx.x * 256 + threadIdx.x;
    const int XN = 4096 * 1024 / 4, W1 = 3072 * 1024 / 4;  // W2 = 1024*1024/4
    float4 v; ushort4* dst;
    if (i < XN)            { v = x[i];            dst = &xb[i]; }
    else if (i < XN + W1)  { v = w1[i - XN];      dst = &w1b[i - XN]; }
    else                   { v = w2[i - XN - W1]; dst = &w2b[i - XN - W1]; }
    ushort4 o;
    o.x = f2bf(v.x); o.y = f2bf(v.y); o.z = f2bf(v.z); o.w = f2bf(v.w);
    *dst = o;
}

// ---------------- QKV GEMM: out[m,n] = sum_k A[m,k]*W[n,k] + bias ------------
// ROUND-0 PROVEN STRUCTURE, fully reverted (r5 post-mortem: the V-transpose
// epilogue cost +4us — 98K LDS bank conflicts, +24 VGPR, extra sync — while
// the 2B V-scatter it replaced was already absorbed by L2 write-combining).
// Tile 128x128, BK=32, 256 thr (4 waves, 2x2; wave-tile 64x64).
// LDS staged via global_load_lds (fragment-ordered), DOUBLE-BUFFERED, one
// barrier per k-iter. Regime [r5 measured]: MFMA 14%, VALU 7%, HBM 12%,
// LDS ~30 B/cyc -> pure latency floor: ~2us/iter x 32 iters. Counted-vmcnt
// pipelining attempts both LOST (r2: 80us coarse, r3: 88us fine) — keep the
// plain 2-barrier loop.
// Epilogue: qkv scatter (Q,K: [B,H,N,D] bf16; V: transposed [B,H,D,N], 2B).
__global__ __launch_bounds__(256) void qkv_gemm(
    const u16* __restrict__ A, const u16* __restrict__ Bw,
    const float* __restrict__ bias,
    u16* __restrict__ Qb, u16* __restrict__ Kb, u16* __restrict__ VTb)
{
    __shared__ __align__(16) u16 Al[2][8 * 512];
    __shared__ __align__(16) u16 Bl[2][8 * 512];
    const int tid = threadIdx.x;
    const int lane = tid & 63;
    const int w = tid >> 6;
    const int la = lane & 15, qd = lane >> 4;
    const int K = 1024;
    const int m0 = blockIdx.y * 128;
    const int n0 = blockIdx.x * 128;
    const int wm = (w >> 1) * 64, wn = (w & 1) * 64;

    const u16* Ag0 = A + (size_t)(m0 + (2 * w) * 16 + la) * K + qd * 8;
    const u16* Ag1 = A + (size_t)(m0 + (2 * w + 1) * 16 + la) * K + qd * 8;
    const u16* Bg0 = Bw + (size_t)(n0 + (2 * w) * 16 + la) * K + qd * 8;
    const u16* Bg1 = Bw + (size_t)(n0 + (2 * w + 1) * 16 + la) * K + qd * 8;

    auto stage = [&](int k0, int b) {
        gl_lds16(Ag0 + k0, &Al[b][(2 * w) * 512]);
        gl_lds16(Ag1 + k0, &Al[b][(2 * w + 1) * 512]);
        gl_lds16(Bg0 + k0, &Bl[b][(2 * w) * 512]);
        gl_lds16(Bg1 + k0, &Bl[b][(2 * w + 1) * 512]);
    };

    f32x4 acc[4][4] = {};
    int buf = 0;
    stage(0, 0);

    for (int k0 = 0; k0 < K; k0 += 32) {
        __syncthreads();                       // drains prev prefetch (vmcnt 0)
        if (k0 + 32 < K) stage(k0 + 32, buf ^ 1);

        bf16x8 af[4], bfr[4];
#pragma unroll
        for (int i = 0; i < 4; i++)
            af[i] = *(const bf16x8*)&Al[buf][(((unsigned)wm >> 4) + i) * 512 + lane * 8];
#pragma unroll
        for (int j = 0; j < 4; j++)
            bfr[j] = *(const bf16x8*)&Bl[buf][(((unsigned)wn >> 4) + j) * 512 + lane * 8];
#pragma unroll
        for (int i = 0; i < 4; i++)
#pragma unroll
            for (int j = 0; j < 4; j++)
                acc[i][j] = __builtin_amdgcn_mfma_f32_16x16x32_bf16(
                    af[i], bfr[j], acc[i][j], 0, 0, 0);
        buf ^= 1;
    }

    // Epilogue. C/D layout: col = lane&15, row = (lane>>4)*4 + reg  [m89-verified]
#pragma unroll
    for (int j = 0; j < 4; j++) {
        const int col = n0 + wn + j * 16 + la;
        const float bv = bias[col];
        const int t = col >> 10, hd = col & 1023, h = hd >> 6, d = hd & 63;
#pragma unroll
        for (int i = 0; i < 4; i++)
#pragma unroll
            for (int r = 0; r < 4; r++) {
                const int row = m0 + wm + i * 16 + qd * 4 + r;
                const int b = row >> 11, n = row & 2047;
                const int bh = b * 16 + h;
                const u16 val = f2bf(acc[i][j][r] + bv);
                if (t == 0)      Qb[((size_t)bh * 2048 + n) * 64 + d] = val;
                else if (t == 1) Kb[((size_t)bh * 2048 + n) * 64 + d] = val;
                else             VTb[((size_t)bh * 64 + d) * 2048 + n] = val;
            }
    }
}

// ---------------- proj GEMM, BK=64: halved barrier count ---------------------
// M=4096, N=1024, K=1024; tile 128x64, grid 16x32 = 512 blocks (2/CU either
// way). r5 theory: GEMM time = iter-count x per-iter latency (~2us, all pipes
// idle). BK=64 -> 16 iters instead of 32; LDS 48KB still allows 3 blocks/CU
// (the m132 BK-regression was the 64KB/2-block case — avoided here).
// LDS chunks: fragment-identity 16 rows x 32 k (1KB); chunk id = g*2+h
// (g = 16-row group, h = k-half). Staging: wave w owns A chunks 4w..4w+3,
// B chunks 2w..2w+1 (6 gl_lds16/wave/iter).
__global__ __launch_bounds__(256) void proj_gemm(
    const u16* __restrict__ A, const u16* __restrict__ Bw,
    const float* __restrict__ bias, float* __restrict__ Out)
{
    __shared__ __align__(16) u16 Al[2][16 * 512];   // 32 KB
    __shared__ __align__(16) u16 Bl[2][8 * 512];    // 16 KB
    const int tid = threadIdx.x;
    const int lane = tid & 63;
    const int w = tid >> 6;
    const int la = lane & 15, qd = lane >> 4;
    const int K = 1024;
    const int m0 = blockIdx.y * 128;
    const int n0 = blockIdx.x * 64;
    const int wm = (w >> 1) * 64, wn = (w & 1) * 32;

    const u16* Asrc[4];
    const u16* Bsrc[2];
#pragma unroll
    for (int t = 0; t < 4; t++) {
        const int ck = 4 * w + t, g = ck >> 1, h = ck & 1;
        Asrc[t] = A + (size_t)(m0 + g * 16 + la) * K + h * 32 + qd * 8;
    }
#pragma unroll
    for (int t = 0; t < 2; t++) {
        const int ck = 2 * w + t, g = ck >> 1, h = ck & 1;
        Bsrc[t] = Bw + (size_t)(n0 + g * 16 + la) * K + h * 32 + qd * 8;
    }
    auto stage = [&](int k0, int b) {
#pragma unroll
        for (int t = 0; t < 4; t++)
            gl_lds16(Asrc[t] + k0, &Al[b][(4 * w + t) * 512]);
#pragma unroll
        for (int t = 0; t < 2; t++)
            gl_lds16(Bsrc[t] + k0, &Bl[b][(2 * w + t) * 512]);
    };

    f32x4 acc[4][2] = {};
    int buf = 0;
    stage(0, 0);

    for (int k0 = 0; k0 < K; k0 += 64) {
        __syncthreads();                       // drains prev prefetch (vmcnt 0)
        if (k0 + 64 < K) stage(k0 + 64, buf ^ 1);

        bf16x8 af[4][2], bfr[2][2];
#pragma unroll
        for (int i = 0; i < 4; i++) {
            const int g = ((unsigned)wm >> 4) + i;
#pragma unroll
            for (int h = 0; h < 2; h++)
                af[i][h] = *(const bf16x8*)&Al[buf][(g * 2 + h) * 512 + lane * 8];
        }
#pragma unroll
        for (int j = 0; j < 2; j++) {
            const int g = ((unsigned)wn >> 4) + j;
#pragma unroll
            for (int h = 0; h < 2; h++)
                bfr[j][h] = *(const bf16x8*)&Bl[buf][(g * 2 + h) * 512 + lane * 8];
        }
#pragma unroll
        for (int i = 0; i < 4; i++)
#pragma unroll
            for (int j = 0; j < 2; j++) {
                f32x4 c = acc[i][j];
                c = __builtin_amdgcn_mfma_f32_16x16x32_bf16(af[i][0], bfr[j][0], c, 0, 0, 0);
                c = __builtin_amdgcn_mfma_f32_16x16x32_bf16(af[i][1], bfr[j][1], c, 0, 0, 0);
                acc[i][j] = c;
            }
        buf ^= 1;
    }

    // Epilogue (fp32 out + bias). C/D layout: col = lane&15, row = qd*4 + r.
#pragma unroll
    for (int j = 0; j < 2; j++) {
        const int col = n0 + wn + j * 16 + la;
        const float bv = bias[col];
#pragma unroll
        for (int i = 0; i < 4; i++)
#pragma unroll
            for (int r = 0; r < 4; r++) {
                const int row = m0 + wm + i * 16 + qd * 4 + r;
                Out[(size_t)row * 1024 + col] = acc[i][j][r] + bv;
            }
    }
}

// ---------------- causal flash attention, LDS-staged, j-step 128 -------------
// 1-D grid of 512: bh = id&31 (XCD affinity -> K/V L2-resident, FETCH 12 MB),
// pair = id>>5 does Q-tiles {pair, 31-pair}. j-tiles of 128 (TWO 64-subtiles
// per barrier): floor(t/2)+1 iters per tile = 17 iters/block for every pair —
// halves the per-iter fixed costs (barrier + vmcnt(0) drain) vs j-step 64.
// K/V double-buffered LDS staged by gl_lds16 (each byte loaded once per BLOCK,
// 4x less L1 traffic than per-wave register loads). Softmax: fixed m=0
// (|S*SL| << 127; identical softmax), S computed transposed (A=K, B=Q -> lane
// owns one q-row, no cross-lane reductions per iter); P round-trips per-wave
// LDS buffer reused for both j-halves (same-wave DS is in-order).
__global__ __launch_bounds__(256) void attn_k(
    const u16* __restrict__ Qb, const u16* __restrict__ Kb,
    const u16* __restrict__ VTb, u16* __restrict__ Ob)
{
    __shared__ __align__(16) u16 Kl[2][16 * 512];   // 32 KB: chunk ck=c*2+h
    __shared__ __align__(16) u16 Vl[2][16 * 512];   // 32 KB: chunk cv=c2*4+kc
    __shared__ __align__(16) u16 Pl[4][16 * 72];    // per-wave P, stride 72
    const int bh = blockIdx.x & 31;
    const int pair = blockIdx.x >> 5;               // 0..15
    const int tid = threadIdx.x;
    const int lane = tid & 63;
    const int w = tid >> 6;
    const int la = lane & 15, qd = lane >> 4;

    const u16* Kbase = Kb + (size_t)bh * 2048 * 64;
    const u16* Vbase = VTb + (size_t)bh * 64 * 2048;
    u16* Pw = &Pl[w][0];

    // staging: wave w stages K chunks 4w..4w+3 and V chunks 4w..4w+3
    u32 ksrc[4], vsrc[4];
#pragma unroll
    for (int t = 0; t < 4; t++) {
        const int ck = 4 * w + t;
        ksrc[t] = (u32)((ck >> 1) * 16 + la) * 64 + (ck & 1) * 32 + qd * 8;
        vsrc[t] = (u32)((ck >> 2) * 16 + la) * 2048 + (ck & 3) * 32 + qd * 8;
    }
    auto stage = [&](int j0, int b) {
#pragma unroll
        for (int t = 0; t < 4; t++) {
            gl_lds16(Kbase + (u32)j0 * 64 + ksrc[t], &Kl[b][(4 * w + t) * 512]);
            gl_lds16(Vbase + (u32)j0 + vsrc[t], &Vl[b][(4 * w + t) * 512]);
        }
    };

    int buf = 0;
    stage(0, 0);                                    // prologue for first tile

    for (int half = 0; half < 2; half++) {
        const int tile = (half == 0) ? pair : 31 - pair;
        const int q0 = tile * 64 + w * 16;
        const int jmax = (tile >> 1) * 128;         // last j128-tile start
        const int qrow = q0 + la;                   // this lane's q-row

        const u16* Qp = Qb + ((size_t)bh * 2048 + q0 + la) * 64 + qd * 8;
        const bf16x8 qf0 = *(const bf16x8*)Qp;
        const bf16x8 qf1 = *(const bf16x8*)(Qp + 32);

        f32x4 o[4] = {};
        float lsum = 0.f;

        for (int j0 = 0; j0 <= jmax; j0 += 128) {
            __syncthreads();   // drains prev prefetch (vmcnt 0, all waves)

            const int nj = (j0 + 128 <= jmax) ? (j0 + 128) : ((half == 0) ? 0 : -1);
            if (nj >= 0) stage(nj, buf ^ 1);

            // S^T = K Q^T : 8 j-subtiles; D[row=j (qd*4+r), col=q (la)]
            f32x4 s[8];
#pragma unroll
            for (int c = 0; c < 8; c++) {
                f32x4 z = {};
                const bf16x8 kf0 = *(const bf16x8*)&Kl[buf][(c * 2 + 0) * 512 + lane * 8];
                const bf16x8 kf1 = *(const bf16x8*)&Kl[buf][(c * 2 + 1) * 512 + lane * 8];
                z = __builtin_amdgcn_mfma_f32_16x16x32_bf16(kf0, qf0, z, 0, 0, 0);
                z = __builtin_amdgcn_mfma_f32_16x16x32_bf16(kf1, qf1, z, 0, 0, 0);
                s[c] = z;
            }

            // p = exp2(s * SL); causal mask only on the diagonal-containing tile
            if (j0 == jmax) {
#pragma unroll
                for (int c = 0; c < 8; c++)
#pragma unroll
                    for (int r = 0; r < 4; r++) {
                        const int j = j0 + c * 16 + qd * 4 + r;
                        float v = s[c][r] * SL_F;
                        v = (j > qrow) ? -1e30f : v;
                        s[c][r] = __builtin_amdgcn_exp2f(v);
                    }
            } else {
#pragma unroll
                for (int c = 0; c < 8; c++)
#pragma unroll
                    for (int r = 0; r < 4; r++)
                        s[c][r] = __builtin_amdgcn_exp2f(s[c][r] * SL_F);
            }
#pragma unroll
            for (int c = 0; c < 8; c++)
#pragma unroll
                for (int r = 0; r < 4; r++)
                    lsum += s[c][r];

            // PV in two j-64 halves, reusing the per-wave P buffer (same-wave
            // DS ops are in-order: the hh=1 writes cannot pass hh=0 reads)
#pragma unroll
            for (int hh = 0; hh < 2; hh++) {
#pragma unroll
                for (int c = 0; c < 4; c++) {
                    uint2 pw;
                    pw.x = pack2bf(s[hh * 4 + c][0], s[hh * 4 + c][1]);
                    pw.y = pack2bf(s[hh * 4 + c][2], s[hh * 4 + c][3]);
                    *(uint2*)&Pw[la * 72 + c * 16 + qd * 4] = pw;
                }
                const bf16x8 pf0 = *(const bf16x8*)&Pw[la * 72 + qd * 8];
                const bf16x8 pf1 = *(const bf16x8*)&Pw[la * 72 + 32 + qd * 8];
#pragma unroll
                for (int c2 = 0; c2 < 4; c2++) {
                    const bf16x8 vf0 = *(const bf16x8*)&Vl[buf][(c2 * 4 + hh * 2 + 0) * 512 + lane * 8];
                    const bf16x8 vf1 = *(const bf16x8*)&Vl[buf][(c2 * 4 + hh * 2 + 1) * 512 + lane * 8];
                    o[c2] = __builtin_amdgcn_mfma_f32_16x16x32_bf16(pf0, vf0, o[c2], 0, 0, 0);
                    o[c2] = __builtin_amdgcn_mfma_f32_16x16x32_bf16(pf1, vf1, o[c2], 0, 0, 0);
                }
            }
            buf ^= 1;
        }

        // reduce l across the 4 quads (lane la holds row la's partials)
        lsum += __shfl_xor(lsum, 16, 64);
        lsum += __shfl_xor(lsum, 32, 64);
        float rinv[4];
#pragma unroll
        for (int r = 0; r < 4; r++)
            rinv[r] = 1.0f / __shfl(lsum, qd * 4 + r, 64);

        // write flat [B,H,N,D] bf16 (== reference's faithful scrambled reshape)
        u16* Op = Ob + (size_t)bh * 2048 * 64;
#pragma unroll
        for (int c2 = 0; c2 < 4; c2++)
#pragma unroll
            for (int r = 0; r < 4; r++) {
                const int row = q0 + qd * 4 + r;
                Op[(size_t)row * 64 + c2 * 16 + la] = f2bf(o[c2][r] * rinv[r]);
            }
    }
}

// ---------------- launch -----------------------------------------------------
extern "C" void kernel_launch(void* const* d_in, const int* in_sizes, int n_in,
                              void* d_out, int out_size, void* d_ws, size_t ws_size,
                              hipStream_t stream)
{
    const float* x     = (const float*)d_in[0];
    // d_in[1] = attention_mask: structurally causal tril; enforced analytically.
    const float* wqkv  = (const float*)d_in[2];
    const float* bqkv  = (const float*)d_in[3];
    const float* wproj = (const float*)d_in[4];
    const float* bproj = (const float*)d_in[5];
    float* out = (float*)d_out;

    // workspace layout (u16 units), ~50 MB total
    u16* ws     = (u16*)d_ws;
    u16* xb     = ws;                       // 4096*1024
    u16* wqkvb  = xb + 4096 * 1024;         // 3072*1024
    u16* wprojb = wqkvb + 3072 * 1024;      // 1024*1024
    u16* Qb     = wprojb + 1024 * 1024;     // 32*2048*64  [B,H,N,D]
    u16* Kb     = Qb + 32 * 2048 * 64;      // 32*2048*64  [B,H,N,D]
    u16* VTb    = Kb + 32 * 2048 * 64;      // 32*64*2048  [B,H,D,N]
    u16* Ob     = VTb + 32 * 2048 * 64;     // 32*2048*64  [B,H,N,D] == scrambled [B*N, C]

    convert_k<<<dim3(8192), dim3(256), 0, stream>>>(
        (const float4*)x, (const float4*)wqkv, (const float4*)wproj,
        (ushort4*)xb, (ushort4*)wqkvb, (ushort4*)wprojb);

    qkv_gemm<<<dim3(24, 32), dim3(256), 0, stream>>>(
        xb, wqkvb, bqkv, Qb, Kb, VTb);

    attn_k<<<dim3(512), dim3(256), 0, stream>>>(Qb, Kb, VTb, Ob);

    // proj: 128x64 tile, BK=64 -> 16 barrier-iters
    proj_gemm<<<dim3(16, 32), dim3(256), 0, stream>>>(
        Ob, wprojb, bproj, out);
}